// Round 15
// baseline (164.213 us; speedup 1.0000x reference)
//
#include <hip/hip_runtime.h>
#include <hip/hip_bf16.h>

// B=2, T=2048, C=1024, H=16, D=64. Inputs/outputs FLOAT32; compute bf16 MFMA.
// R22 (single change vs R21): gemm_qkv tile 64x128 -> 128x96.
//  Arithmetic: LDS b128/MFMA = (af+bf)/(i*j): 6/8=0.75 at 64x128 ->
//  7/12=0.583 at 128x96 (acc[4][3]) = -22% LDS traffic (port was ~62% busy).
//  Grid stays big: 32x32 = 1024 blocks = 4/CU (128^2's 768 was the occupancy
//  trap). LDS 28KB, acc 48 VGPR, launch_bounds(256,4).
//  96-wide tile audit: every j-16 column group lies wholly in one of q/k/v
//  (1024%16=0) -> per-j 'which' logic unchanged; B staging rows 8-aligned
//  per gll16 instr (wave*24+s*8) -> granule-XOR source trick unchanged.
// proj unchanged (R21 64x64). attn unchanged (R17 T15 skew). prep unchanged.

typedef __bf16 bf16x8 __attribute__((ext_vector_type(8)));
typedef float  f32x4  __attribute__((ext_vector_type(4)));
#define BF16 __hip_bfloat16

constexpr int Bb = 2, Tt = 2048, Cc = 1024, Hh = 16, Dd = 64;
constexpr float NEG_INF = -1e30f;
constexpr float Q_SCALE = 0.18033688011112042f;   // (1/8) * log2(e)
constexpr float EXP2_BIAS = 17.312340490667562f;  // 12 * log2(e)

__device__ __forceinline__ f32x4 mfma16(bf16x8 a, bf16x8 b, f32x4 c) {
  return __builtin_amdgcn_mfma_f32_16x16x32_bf16(a, b, c, 0, 0, 0);
}

// raw v_exp_f32 (exp2): 1 trans instr, no OCML denormal guard.
__device__ __forceinline__ float fast_exp2(float x) {
  float r;
  asm("v_exp_f32 %0, %1" : "=v"(r) : "v"(x));
  return r;
}

// async global->LDS, 16B per lane; LDS dest = wave-uniform base + lane*16.
__device__ __forceinline__ void gll16(const void* g, void* l) {
  __builtin_amdgcn_global_load_lds((const __attribute__((address_space(1))) void*)g,
                                   (__attribute__((address_space(3))) void*)l,
                                   16, 0, 0);
}

// 7-bit inverse K-row permutation (LDS row -> global key).
// row{c1,c0,t,q1,q0,r1,r0} -> key{c1,c0,q1,q0,t,r1,r0}.
__device__ __forceinline__ int kperm_inv7(int r) {
  return (r & 0x63) | ((r & 0x0C) << 1) | ((r & 0x10) >> 2);
}

// Fused prep: blocks [0,2048) cast x f32->bf16 (8/thread);
// [2048,5120) transpose+cast W_attn; [5120,6144) transpose+cast W_proj.
__global__ void prep_kernel(const float* __restrict__ x, BF16* __restrict__ xb,
                            const float* __restrict__ Wa, BF16* __restrict__ WaT,
                            const float* __restrict__ Wp, BF16* __restrict__ WpT) {
  __shared__ float tile[32][33];
  const int bx = blockIdx.x, tid = threadIdx.x;
  if (bx < 2048) {
    const int i = (bx * 256 + tid) * 8;
    const float4 a = *(const float4*)&x[i];
    const float4 b = *(const float4*)&x[i + 4];
    BF16 o[8];
    o[0] = __float2bfloat16(a.x); o[1] = __float2bfloat16(a.y);
    o[2] = __float2bfloat16(a.z); o[3] = __float2bfloat16(a.w);
    o[4] = __float2bfloat16(b.x); o[5] = __float2bfloat16(b.y);
    o[6] = __float2bfloat16(b.z); o[7] = __float2bfloat16(b.w);
    *(uint4*)&xb[i] = *(const uint4*)o;
    return;
  }
  const float* in; BF16* outT; int K, N, gx, gy;
  if (bx < 5120) {
    const int idx = bx - 2048;
    in = Wa; outT = WaT; K = 1024; N = 3072; gx = idx % 96; gy = idx / 96;
  } else {
    const int idx = bx - 5120;
    in = Wp; outT = WpT; K = 1024; N = 1024; gx = idx % 32; gy = idx / 32;
  }
  const int n0 = gx * 32, k0 = gy * 32;
  const int tx = tid & 31, ty = tid >> 5;
#pragma unroll
  for (int i = ty; i < 32; i += 8) tile[i][tx] = in[(size_t)(k0 + i) * N + (n0 + tx)];
  __syncthreads();
#pragma unroll
  for (int i = ty; i < 32; i += 8)
    outT[(size_t)(n0 + i) * K + (k0 + tx)] = __float2bfloat16(tile[tx][i]);
}

// QKV GEMM: C[m][n] = sum_k A[m][k]*Bt[n][k] + bias[n]. 128x96 tile, BK=64,
// 2-phase, 1024 blocks = 4/CU. acc[4][3] -> 0.583 LDS b128/MFMA.
// LDS granule-XOR swizzled via pre-swizzled global source (0 conflicts).
// Scatter q/k [B,H,T,D] bf16 (q pre-scaled log2e/8), V transposed [B,H,D,T].
__global__ __launch_bounds__(256, 4) void gemm_qkv(const BF16* __restrict__ A,
                                                   const BF16* __restrict__ Bt,
                                                   const float* __restrict__ bias,
                                                   BF16* __restrict__ oq,
                                                   BF16* __restrict__ ok,
                                                   BF16* __restrict__ ov) {
  __shared__ alignas(16) BF16 sA[128 * 64];
  __shared__ alignas(16) BF16 sB[96 * 64];
  const int Kdim = 1024;
  const int tid = threadIdx.x;
  const int wave = tid >> 6, lane = tid & 63;
  const int quad = lane >> 4, l16 = lane & 15;
  const int wm = (wave >> 1) * 64, wn = (wave & 1) * 48;
  const int bm = blockIdx.y * 128, bn = blockIdx.x * 96;
  const int sw = l16 & 7;  // read-side swizzle key (= row&7 for row base%8==0)

  f32x4 acc[4][3];
#pragma unroll
  for (int i = 0; i < 4; ++i)
#pragma unroll
    for (int j = 0; j < 3; ++j) acc[i][j] = f32x4{0.f, 0.f, 0.f, 0.f};

  // Staging: A rows wave*32 + s*8 + (lane>>3), s=0..3;
  //          B rows wave*24 + s*8 + (lane>>3), s=0..2. Rows 8-aligned/instr.
  const int sgl = (lane ^ (lane >> 3)) & 7;
  const BF16* gA0 = &A[(size_t)(bm + wave * 32 + (lane >> 3)) * Kdim + sgl * 8];
  const BF16* gB0 = &Bt[(size_t)(bn + wave * 24 + (lane >> 3)) * Kdim + sgl * 8];
  const size_t rstep8 = (size_t)8 * Kdim;

  for (int k0 = 0; k0 < Kdim; k0 += 64) {
    __syncthreads();  // WAR: all waves done reading previous tile
#pragma unroll
    for (int s = 0; s < 4; ++s)
      gll16(gA0 + s * rstep8 + k0, &sA[wave * 2048 + s * 512]);
#pragma unroll
    for (int s = 0; s < 3; ++s)
      gll16(gB0 + s * rstep8 + k0, &sB[wave * 1536 + s * 512]);
    __syncthreads();  // compiler drains vmcnt(0) before barrier -> tile visible

#pragma unroll
    for (int h = 0; h < 2; ++h) {
      bf16x8 af[4], bf_[3];
#pragma unroll
      for (int i = 0; i < 4; ++i)
        af[i] = *(const bf16x8*)
            &sA[(wm + i * 16 + l16) * 64 + (((h * 4 + quad) ^ sw) << 3)];
#pragma unroll
      for (int j = 0; j < 3; ++j)
        bf_[j] = *(const bf16x8*)
            &sB[(wn + j * 16 + l16) * 64 + (((h * 4 + quad) ^ sw) << 3)];
#pragma unroll
      for (int i = 0; i < 4; ++i)
#pragma unroll
        for (int j = 0; j < 3; ++j) acc[i][j] = mfma16(af[i], bf_[j], acc[i][j]);
    }
  }

#pragma unroll
  for (int j = 0; j < 3; ++j) {
    const int gn = bn + wn + j * 16 + l16;
    const float bsv = bias[gn];
    // which is wave-uniform per j: each 16-col group lies in one of q/k/v.
    const int which = (bn + wn + j * 16) >> 10;
    const int c = gn & 1023;
    const int hh = c >> 6, dd = c & 63;
#pragma unroll
    for (int i = 0; i < 4; ++i) {
      const int gm0 = bm + wm + i * 16 + quad * 4;  // 4-aligned: bb/tk0 uniform over r
      const int bb = gm0 >> 11, tk0 = gm0 & 2047;
      const size_t bh = (size_t)(bb * Hh + hh);
      if (which == 2) {
        // V: transposed [B,H,D,T]; r-accs are contiguous t -> one 8B store.
        BF16 tmp[4];
#pragma unroll
        for (int r = 0; r < 4; ++r) tmp[r] = __float2bfloat16(acc[i][j][r] + bsv);
        *(uint2*)&ov[(bh * Dd + dd) * Tt + tk0] = *(const uint2*)tmp;
      } else {
        BF16* dst = (which == 0) ? oq : ok;
        const float scale = (which == 0) ? Q_SCALE : 1.0f;
#pragma unroll
        for (int r = 0; r < 4; ++r)
          dst[(bh * Tt + tk0 + r) * Dd + dd] =
              __float2bfloat16((acc[i][j][r] + bsv) * scale);
      }
    }
  }
}

// Proj GEMM: fout[m][n] = sum_k A[m][k]*Bt[n][k] + bias[n], M=4096 N=1024.
// 64x64 tile -> 1024 blocks, 16KB LDS, launch_bounds(256,6) (R21).
__global__ __launch_bounds__(256, 6) void gemm_proj(const BF16* __restrict__ A,
                                                    const BF16* __restrict__ Bt,
                                                    const float* __restrict__ bias,
                                                    float* __restrict__ fout) {
  __shared__ alignas(16) BF16 sA[64 * 64];
  __shared__ alignas(16) BF16 sB[64 * 64];
  const int Kdim = 1024, Ndim = 1024;
  const int tid = threadIdx.x;
  const int wave = tid >> 6, lane = tid & 63;
  const int quad = lane >> 4, l16 = lane & 15;
  const int wm = (wave >> 1) * 32, wn = (wave & 1) * 32;
  const int bm = blockIdx.y * 64, bn = blockIdx.x * 64;
  const int sw = l16 & 7;

  f32x4 acc[2][2];
#pragma unroll
  for (int i = 0; i < 2; ++i)
#pragma unroll
    for (int j = 0; j < 2; ++j) acc[i][j] = f32x4{0.f, 0.f, 0.f, 0.f};

  // A,B: rows wave*16 + s*8 + (lane>>3), s=0..1. Rows 8-aligned per instr.
  const int sgl = (lane ^ (lane >> 3)) & 7;
  const BF16* gA0 = &A[(size_t)(bm + wave * 16 + (lane >> 3)) * Kdim + sgl * 8];
  const BF16* gB0 = &Bt[(size_t)(bn + wave * 16 + (lane >> 3)) * Kdim + sgl * 8];
  const size_t rstep8 = (size_t)8 * Kdim;

  for (int k0 = 0; k0 < Kdim; k0 += 64) {
    __syncthreads();
#pragma unroll
    for (int s = 0; s < 2; ++s) {
      gll16(gA0 + s * rstep8 + k0, &sA[wave * 1024 + s * 512]);
      gll16(gB0 + s * rstep8 + k0, &sB[wave * 1024 + s * 512]);
    }
    __syncthreads();

#pragma unroll
    for (int h = 0; h < 2; ++h) {
      bf16x8 af[2], bf_[2];
#pragma unroll
      for (int i = 0; i < 2; ++i)
        af[i] = *(const bf16x8*)
            &sA[(wm + i * 16 + l16) * 64 + (((h * 4 + quad) ^ sw) << 3)];
#pragma unroll
      for (int j = 0; j < 2; ++j)
        bf_[j] = *(const bf16x8*)
            &sB[(wn + j * 16 + l16) * 64 + (((h * 4 + quad) ^ sw) << 3)];
#pragma unroll
      for (int i = 0; i < 2; ++i)
#pragma unroll
        for (int j = 0; j < 2; ++j) acc[i][j] = mfma16(af[i], bf_[j], acc[i][j]);
    }
  }

#pragma unroll
  for (int j = 0; j < 2; ++j) {
    const int gn = bn + wn + j * 16 + l16;
    const float bsv = bias[gn];
#pragma unroll
    for (int i = 0; i < 2; ++i)
#pragma unroll
      for (int r = 0; r < 4; ++r) {
        const int gm = bm + wm + i * 16 + quad * 4 + r;
        fout[(size_t)gm * Ndim + gn] = acc[i][j][r] + bsv;
      }
  }
}

// Causal flash attention, KVBLK=128, T15-skewed pipeline (R17, unchanged).
__global__ __launch_bounds__(256) void attn_kernel(const BF16* __restrict__ qg,
                                                   const BF16* __restrict__ kg,
                                                   const BF16* __restrict__ vtg,
                                                   BF16* __restrict__ yb) {
  __shared__ alignas(16) BF16 sK[2 * 8192];  // [buf][perm_key 128][d 64]
  __shared__ alignas(16) BF16 sV[2 * 8192];  // [buf][d 64][key 128]
  const int id = blockIdx.x;
  const int xcd = id & 7, local = id >> 3;      // blockIdx%8 round-robins XCDs
  const int bh = xcd * 4 + (local & 3);         // 4 (b,h) per XCD: 2MB K/V in L2
  const int s = 31 - (local >> 2);              // 64-row strip, long first
  const int b = bh >> 4, h = bh & 15;
  const int tid = threadIdx.x;
  const int wave = tid >> 6, lane = tid & 63;
  const int quad = lane >> 4, l16 = lane & 15;
  const size_t base = ((size_t)(b * Hh + h)) * Tt * Dd;
  const int qrow0 = s * 64 + wave * 16;
  const int sw = l16 & 7;

  // Q fragment (B-operand: lane n=l16 holds Q[qrow0+l16][k=quad*8+j])
  bf16x8 qf0, qf1;
  {
    const size_t off = base + (size_t)(qrow0 + l16) * Dd;
    qf0 = *(const bf16x8*)&qg[off + quad * 8];
    qf1 = *(const bf16x8*)&qg[off + 32 + quad * 8];
  }

  bf16x8 ones8;
#pragma unroll
  for (int j = 0; j < 8; ++j) ones8[j] = (__bf16)1.0f;

  f32x4 o[4], oL;
#pragma unroll
  for (int i = 0; i < 4; ++i) o[i] = f32x4{0.f, 0.f, 0.f, 0.f};
  oL = f32x4{0.f, 0.f, 0.f, 0.f};

  const f32x4 cbias = f32x4{-EXP2_BIAS, -EXP2_BIAS, -EXP2_BIAS, -EXP2_BIAS};

  // Staging (per thread, 4 K + 4 V gll16 per tile).
  const int t = tid;
  const int sgk = (t ^ (t >> 3)) & 7;
  const int sgv = (t ^ (t >> 4)) & 15;
  const BF16* pk[4];
  const BF16* pv[4];
#pragma unroll
  for (int i = 0; i < 4; ++i) {
    pk[i] = &kg[base + (size_t)kperm_inv7(i * 32 + (t >> 3)) * Dd + sgk * 8];
    pv[i] = &vtg[base + (size_t)(i * 16 + (t >> 4)) * Tt + sgv * 8];
  }

#define STAGE_K(buf, tt_)                                            \
  do {                                                               \
    const size_t ko_ = (size_t)(tt_) * 8192;                         \
    _Pragma("unroll") for (int i_ = 0; i_ < 4; ++i_)                 \
        gll16(pk[i_] + ko_, &sK[(buf) * 8192 + i_ * 2048 + t * 8]);  \
  } while (0)
#define STAGE_V(buf, tt_)                                            \
  do {                                                               \
    const int vo_ = (tt_) * 128;                                     \
    _Pragma("unroll") for (int i_ = 0; i_ < 4; ++i_)                 \
        gll16(pv[i_] + vo_, &sV[(buf) * 8192 + i_ * 2048 + t * 8]);  \
  } while (0)

#define QK_TILE(jt_)                                                        \
  do {                                                                      \
    const BF16* sKb_ = &sK[((jt_) & 1) * 8192];                             \
    __builtin_amdgcn_s_setprio(1);                                          \
    _Pragma("unroll") for (int tt = 0; tt < 8; ++tt) {                      \
      const bf16x8 kf0 =                                                    \
          *(const bf16x8*)&sKb_[(tt * 16 + l16) * 64 + ((quad ^ sw) << 3)]; \
      const bf16x8 kf1 = *(const bf16x8*)                                   \
          &sKb_[(tt * 16 + l16) * 64 + (((4 + quad) ^ sw) << 3)];           \
      sS[tt] = mfma16(kf0, qf0, cbias);                                     \
      sS[tt] = mfma16(kf1, qf1, sS[tt]);                                    \
    }                                                                       \
    __builtin_amdgcn_s_setprio(0);                                          \
  } while (0)

#define MASK_TILE(jt_)                                                  \
  do {                                                                  \
    const int kb_ = (jt_) * 128;                                        \
    const int q_ = qrow0 + l16;                                         \
    _Pragma("unroll") for (int tt = 0; tt < 8; ++tt) {                  \
      const int kc0 = kb_ + (tt >> 1) * 32 + quad * 8 + (tt & 1) * 4;   \
      _Pragma("unroll") for (int r = 0; r < 4; ++r)                     \
          if (kc0 + r > q_) sS[tt][r] = NEG_INF;                        \
    }                                                                   \
  } while (0)

#define EXP_P()                                                          \
  do {                                                                   \
    _Pragma("unroll") for (int cc = 0; cc < 4; ++cc)                     \
        _Pragma("unroll") for (int j = 0; j < 8; ++j)                    \
            pf[cc][j] = (__bf16)fast_exp2(sS[cc * 2 + (j >> 2)][j & 3]); \
  } while (0)

#define PV_TILE(jt_)                                                          \
  do {                                                                        \
    const BF16* sVb_ = &sV[((jt_) & 1) * 8192];                               \
    __builtin_amdgcn_s_setprio(1);                                            \
    _Pragma("unroll") for (int cc = 0; cc < 4; ++cc) {                        \
      _Pragma("unroll") for (int dt = 0; dt < 4; ++dt) {                      \
        const bf16x8 vb = *(const bf16x8*)                                    \
            &sVb_[(dt * 16 + l16) * 128 +                                     \
                  ((((cc * 4 + quad) ^ l16) & 15) << 3)];                     \
        o[dt] = mfma16(pf[cc], vb, o[dt]);                                    \
      }                                                                       \
      oL = mfma16(pf[cc], ones8, oL);                                         \
    }                                                                         \
    __builtin_amdgcn_s_setprio(0);                                            \
  } while (0)

  const int nt = (s + 2) >> 1;  // tiles of 128 keys
  f32x4 sS[8];
  bf16x8 pf[4];

  // prologue: K(0) in flight
  STAGE_K(0, 0);

  // iter 0: QK(0) only
  asm volatile("s_waitcnt vmcnt(0)" ::: "memory");
  __builtin_amdgcn_s_barrier();
  STAGE_V(0, 0);
  if (nt > 1) STAGE_K(1, 1);
  QK_TILE(0);
  if (nt == 1) MASK_TILE(0);

  // main iters 1..nt-1: exp/PV(jt-1) || QK(jt)
  for (int jt = 1; jt < nt; ++jt) {
    asm volatile("s_waitcnt vmcnt(0)" ::: "memory");
    __builtin_amdgcn_s_barrier();
    STAGE_V(jt & 1, jt);
    if (jt + 1 < nt) STAGE_K((jt + 1) & 1, jt + 1);
    EXP_P();       // VALU, reads sS of tile jt-1 (independent of QK below)
    QK_TILE(jt);   // MFMA, overlaps EXP_P in the same straight-line block
    if (jt == nt - 1) MASK_TILE(jt);
    PV_TILE(jt - 1);
  }

  // final iter nt: exp/PV of tile nt-1
  asm volatile("s_waitcnt vmcnt(0)" ::: "memory");
  __builtin_amdgcn_s_barrier();
  EXP_P();
  PV_TILE(nt - 1);

#undef STAGE_K
#undef STAGE_V
#undef QK_TILE
#undef MASK_TILE
#undef EXP_P
#undef PV_TILE

  // epilogue: C-layout row quad*4+r = q, col dt*16+l16 = d
#pragma unroll
  for (int r = 0; r < 4; ++r) {
    const float inv = 1.0f / oL[r];
    const int trow = qrow0 + quad * 4 + r;
#pragma unroll
    for (int dt = 0; dt < 4; ++dt)
      yb[((size_t)(b * Tt + trow)) * Cc + h * Dd + dt * 16 + l16] =
          __float2bfloat16(o[dt][r] * inv);
  }
}

extern "C" void kernel_launch(void* const* d_in, const int* in_sizes, int n_in,
                              void* d_out, int out_size, void* d_ws, size_t ws_size,
                              hipStream_t stream) {
  (void)in_sizes; (void)n_in; (void)out_size; (void)ws_size;
  const float* x      = (const float*)d_in[0];
  const float* W_attn = (const float*)d_in[1];
  const float* b_attn = (const float*)d_in[2];
  const float* W_proj = (const float*)d_in[3];
  const float* b_proj = (const float*)d_in[4];
  float* out = (float*)d_out;

  constexpr size_t SZ_WA = (size_t)3072 * 1024;
  constexpr size_t SZ_WP = (size_t)1024 * 1024;
  constexpr size_t SZ_X  = (size_t)4096 * 1024;
  constexpr size_t SZ_T  = (size_t)Bb * Hh * Tt * Dd;

  BF16* ws   = (BF16*)d_ws;
  BF16* wtAb = ws;
  BF16* wtPb = wtAb + SZ_WA;
  BF16* xb   = wtPb + SZ_WP;
  BF16* q    = xb + SZ_X;
  BF16* k    = q + SZ_T;
  BF16* vt   = k + SZ_T;
  BF16* yb   = vt + SZ_T;

  prep_kernel<<<dim3(6144), 256, 0, stream>>>(x, xb, W_attn, wtAb, W_proj, wtPb);
  gemm_qkv<<<dim3(32, 32), 256, 0, stream>>>(xb, wtAb, b_attn, q, k, vt);
  attn_kernel<<<dim3(1024), 256, 0, stream>>>(q, k, vt, yb);
  gemm_proj<<<dim3(16, 64), 256, 0, stream>>>(yb, wtPb, b_proj, out);
}

// Round 16
// 163.070 us; speedup vs baseline: 1.0070x; 1.0070x over previous
//
#include <hip/hip_runtime.h>
#include <hip/hip_bf16.h>

// B=2, T=2048, C=1024, H=16, D=64. Inputs/outputs FLOAT32; compute bf16 MFMA.
// R23: revert QKV to R21's 64x128 (R22's 128x96 reuse-for-TLP trade lost:
// 4/CU@0.583 < 6/CU@0.75 — TLP dominates in this short-K regime, 4th data
// point) + ONE new variable: T1 XCD chunk-swizzle on gemm_qkv block mapping.
//  Mechanism: FETCH_SIZE 40MB vs 14MB ideal -> A/B re-reads miss L2, served
//  by L3 (~900cy vs ~200cy). Remap so each XCD owns 8 consecutive bm-rows
//  (all 24 bn): per-XCD A working set 1MB < 4MB L2 -> A re-reads become L2
//  hits. Bijective (1536 = 8*192). Grid flattened to 1D.
// proj unchanged (R21 64x64). attn unchanged (R17 T15 skew). prep unchanged.

typedef __bf16 bf16x8 __attribute__((ext_vector_type(8)));
typedef float  f32x4  __attribute__((ext_vector_type(4)));
#define BF16 __hip_bfloat16

constexpr int Bb = 2, Tt = 2048, Cc = 1024, Hh = 16, Dd = 64;
constexpr float NEG_INF = -1e30f;
constexpr float Q_SCALE = 0.18033688011112042f;   // (1/8) * log2(e)
constexpr float EXP2_BIAS = 17.312340490667562f;  // 12 * log2(e)

__device__ __forceinline__ f32x4 mfma16(bf16x8 a, bf16x8 b, f32x4 c) {
  return __builtin_amdgcn_mfma_f32_16x16x32_bf16(a, b, c, 0, 0, 0);
}

// raw v_exp_f32 (exp2): 1 trans instr, no OCML denormal guard.
__device__ __forceinline__ float fast_exp2(float x) {
  float r;
  asm("v_exp_f32 %0, %1" : "=v"(r) : "v"(x));
  return r;
}

// async global->LDS, 16B per lane; LDS dest = wave-uniform base + lane*16.
__device__ __forceinline__ void gll16(const void* g, void* l) {
  __builtin_amdgcn_global_load_lds((const __attribute__((address_space(1))) void*)g,
                                   (__attribute__((address_space(3))) void*)l,
                                   16, 0, 0);
}

// 7-bit inverse K-row permutation (LDS row -> global key).
// row{c1,c0,t,q1,q0,r1,r0} -> key{c1,c0,q1,q0,t,r1,r0}.
__device__ __forceinline__ int kperm_inv7(int r) {
  return (r & 0x63) | ((r & 0x0C) << 1) | ((r & 0x10) >> 2);
}

// Fused prep: blocks [0,2048) cast x f32->bf16 (8/thread);
// [2048,5120) transpose+cast W_attn; [5120,6144) transpose+cast W_proj.
__global__ void prep_kernel(const float* __restrict__ x, BF16* __restrict__ xb,
                            const float* __restrict__ Wa, BF16* __restrict__ WaT,
                            const float* __restrict__ Wp, BF16* __restrict__ WpT) {
  __shared__ float tile[32][33];
  const int bx = blockIdx.x, tid = threadIdx.x;
  if (bx < 2048) {
    const int i = (bx * 256 + tid) * 8;
    const float4 a = *(const float4*)&x[i];
    const float4 b = *(const float4*)&x[i + 4];
    BF16 o[8];
    o[0] = __float2bfloat16(a.x); o[1] = __float2bfloat16(a.y);
    o[2] = __float2bfloat16(a.z); o[3] = __float2bfloat16(a.w);
    o[4] = __float2bfloat16(b.x); o[5] = __float2bfloat16(b.y);
    o[6] = __float2bfloat16(b.z); o[7] = __float2bfloat16(b.w);
    *(uint4*)&xb[i] = *(const uint4*)o;
    return;
  }
  const float* in; BF16* outT; int K, N, gx, gy;
  if (bx < 5120) {
    const int idx = bx - 2048;
    in = Wa; outT = WaT; K = 1024; N = 3072; gx = idx % 96; gy = idx / 96;
  } else {
    const int idx = bx - 5120;
    in = Wp; outT = WpT; K = 1024; N = 1024; gx = idx % 32; gy = idx / 32;
  }
  const int n0 = gx * 32, k0 = gy * 32;
  const int tx = tid & 31, ty = tid >> 5;
#pragma unroll
  for (int i = ty; i < 32; i += 8) tile[i][tx] = in[(size_t)(k0 + i) * N + (n0 + tx)];
  __syncthreads();
#pragma unroll
  for (int i = ty; i < 32; i += 8)
    outT[(size_t)(n0 + i) * K + (k0 + tx)] = __float2bfloat16(tile[tx][i]);
}

// QKV GEMM: C[m][n] = sum_k A[m][k]*Bt[n][k] + bias[n]. 64x128 tile, BK=64,
// 2-phase, 1536 blocks (6/CU TLP) with XCD chunk-swizzle: each XCD owns 8
// consecutive bm-rows x all 24 bn -> A working set 1MB, L2-resident.
// LDS granule-XOR swizzled via pre-swizzled global source (0 conflicts).
// Scatter q/k [B,H,T,D] bf16 (q pre-scaled log2e/8), V transposed [B,H,D,T].
__global__ __launch_bounds__(256, 6) void gemm_qkv(const BF16* __restrict__ A,
                                                   const BF16* __restrict__ Bt,
                                                   const float* __restrict__ bias,
                                                   BF16* __restrict__ oq,
                                                   BF16* __restrict__ ok,
                                                   BF16* __restrict__ ov) {
  __shared__ alignas(16) BF16 sA[64 * 64];
  __shared__ alignas(16) BF16 sB[128 * 64];
  const int Kdim = 1024;
  // XCD chunk-swizzle: lin%8 = XCD; give each XCD 192 consecutive work ids
  // = 8 bm-rows x 24 bn tiles (bijective: 1536 = 8*192).
  const int lin = blockIdx.x;
  const int lin2 = (lin & 7) * 192 + (lin >> 3);
  const int bm = (lin2 / 24) * 64, bn = (lin2 % 24) * 128;
  const int tid = threadIdx.x;
  const int wave = tid >> 6, lane = tid & 63;
  const int quad = lane >> 4, l16 = lane & 15;
  const int wm = (wave >> 1) * 32, wn = (wave & 1) * 64;
  const int sw = l16 & 7;  // read-side swizzle key (= row&7 for row base%8==0)

  f32x4 acc[2][4];
#pragma unroll
  for (int i = 0; i < 2; ++i)
#pragma unroll
    for (int j = 0; j < 4; ++j) acc[i][j] = f32x4{0.f, 0.f, 0.f, 0.f};

  // Staging: A rows wave*16 + s*8 + (lane>>3), s=0..1;
  //          B rows wave*32 + s*8 + (lane>>3), s=0..3. Rows 8-aligned/instr.
  const int sgl = (lane ^ (lane >> 3)) & 7;
  const BF16* gA0 = &A[(size_t)(bm + wave * 16 + (lane >> 3)) * Kdim + sgl * 8];
  const BF16* gB0 = &Bt[(size_t)(bn + wave * 32 + (lane >> 3)) * Kdim + sgl * 8];
  const size_t rstep8 = (size_t)8 * Kdim;

  for (int k0 = 0; k0 < Kdim; k0 += 64) {
    __syncthreads();  // WAR: all waves done reading previous tile
#pragma unroll
    for (int s = 0; s < 2; ++s)
      gll16(gA0 + s * rstep8 + k0, &sA[wave * 1024 + s * 512]);
#pragma unroll
    for (int s = 0; s < 4; ++s)
      gll16(gB0 + s * rstep8 + k0, &sB[wave * 2048 + s * 512]);
    __syncthreads();  // compiler drains vmcnt(0) before barrier -> tile visible

#pragma unroll
    for (int h = 0; h < 2; ++h) {
      bf16x8 af[2], bf_[4];
#pragma unroll
      for (int i = 0; i < 2; ++i)
        af[i] = *(const bf16x8*)
            &sA[(wm + i * 16 + l16) * 64 + (((h * 4 + quad) ^ sw) << 3)];
#pragma unroll
      for (int j = 0; j < 4; ++j)
        bf_[j] = *(const bf16x8*)
            &sB[(wn + j * 16 + l16) * 64 + (((h * 4 + quad) ^ sw) << 3)];
#pragma unroll
      for (int i = 0; i < 2; ++i)
#pragma unroll
        for (int j = 0; j < 4; ++j) acc[i][j] = mfma16(af[i], bf_[j], acc[i][j]);
    }
  }

#pragma unroll
  for (int j = 0; j < 4; ++j) {
    const int gn = bn + wn + j * 16 + l16;
    const float bsv = bias[gn];
    // which is wave-uniform per j: gn span is 16-aligned, never crosses 1024.
    const int which = (bn + wn + j * 16) >> 10;
    const int c = gn & 1023;
    const int hh = c >> 6, dd = c & 63;
#pragma unroll
    for (int i = 0; i < 2; ++i) {
      const int gm0 = bm + wm + i * 16 + quad * 4;  // 4-aligned: bb/tk0 uniform over r
      const int bb = gm0 >> 11, tk0 = gm0 & 2047;
      const size_t bh = (size_t)(bb * Hh + hh);
      if (which == 2) {
        // V: transposed [B,H,D,T]; r-accs are contiguous t -> one 8B store.
        BF16 tmp[4];
#pragma unroll
        for (int r = 0; r < 4; ++r) tmp[r] = __float2bfloat16(acc[i][j][r] + bsv);
        *(uint2*)&ov[(bh * Dd + dd) * Tt + tk0] = *(const uint2*)tmp;
      } else {
        BF16* dst = (which == 0) ? oq : ok;
        const float scale = (which == 0) ? Q_SCALE : 1.0f;
#pragma unroll
        for (int r = 0; r < 4; ++r)
          dst[(bh * Tt + tk0 + r) * Dd + dd] =
              __float2bfloat16((acc[i][j][r] + bsv) * scale);
      }
    }
  }
}

// Proj GEMM: fout[m][n] = sum_k A[m][k]*Bt[n][k] + bias[n], M=4096 N=1024.
// 64x64 tile -> 1024 blocks, 16KB LDS, launch_bounds(256,6) (R21).
__global__ __launch_bounds__(256, 6) void gemm_proj(const BF16* __restrict__ A,
                                                    const BF16* __restrict__ Bt,
                                                    const float* __restrict__ bias,
                                                    float* __restrict__ fout) {
  __shared__ alignas(16) BF16 sA[64 * 64];
  __shared__ alignas(16) BF16 sB[64 * 64];
  const int Kdim = 1024, Ndim = 1024;
  const int tid = threadIdx.x;
  const int wave = tid >> 6, lane = tid & 63;
  const int quad = lane >> 4, l16 = lane & 15;
  const int wm = (wave >> 1) * 32, wn = (wave & 1) * 32;
  const int bm = blockIdx.y * 64, bn = blockIdx.x * 64;
  const int sw = l16 & 7;

  f32x4 acc[2][2];
#pragma unroll
  for (int i = 0; i < 2; ++i)
#pragma unroll
    for (int j = 0; j < 2; ++j) acc[i][j] = f32x4{0.f, 0.f, 0.f, 0.f};

  // A,B: rows wave*16 + s*8 + (lane>>3), s=0..1. Rows 8-aligned per instr.
  const int sgl = (lane ^ (lane >> 3)) & 7;
  const BF16* gA0 = &A[(size_t)(bm + wave * 16 + (lane >> 3)) * Kdim + sgl * 8];
  const BF16* gB0 = &Bt[(size_t)(bn + wave * 16 + (lane >> 3)) * Kdim + sgl * 8];
  const size_t rstep8 = (size_t)8 * Kdim;

  for (int k0 = 0; k0 < Kdim; k0 += 64) {
    __syncthreads();
#pragma unroll
    for (int s = 0; s < 2; ++s) {
      gll16(gA0 + s * rstep8 + k0, &sA[wave * 1024 + s * 512]);
      gll16(gB0 + s * rstep8 + k0, &sB[wave * 1024 + s * 512]);
    }
    __syncthreads();

#pragma unroll
    for (int h = 0; h < 2; ++h) {
      bf16x8 af[2], bf_[2];
#pragma unroll
      for (int i = 0; i < 2; ++i)
        af[i] = *(const bf16x8*)
            &sA[(wm + i * 16 + l16) * 64 + (((h * 4 + quad) ^ sw) << 3)];
#pragma unroll
      for (int j = 0; j < 2; ++j)
        bf_[j] = *(const bf16x8*)
            &sB[(wn + j * 16 + l16) * 64 + (((h * 4 + quad) ^ sw) << 3)];
#pragma unroll
      for (int i = 0; i < 2; ++i)
#pragma unroll
        for (int j = 0; j < 2; ++j) acc[i][j] = mfma16(af[i], bf_[j], acc[i][j]);
    }
  }

#pragma unroll
  for (int j = 0; j < 2; ++j) {
    const int gn = bn + wn + j * 16 + l16;
    const float bsv = bias[gn];
#pragma unroll
    for (int i = 0; i < 2; ++i)
#pragma unroll
      for (int r = 0; r < 4; ++r) {
        const int gm = bm + wm + i * 16 + quad * 4 + r;
        fout[(size_t)gm * Ndim + gn] = acc[i][j][r] + bsv;
      }
  }
}

// Causal flash attention, KVBLK=128, T15-skewed pipeline (R17, unchanged).
__global__ __launch_bounds__(256) void attn_kernel(const BF16* __restrict__ qg,
                                                   const BF16* __restrict__ kg,
                                                   const BF16* __restrict__ vtg,
                                                   BF16* __restrict__ yb) {
  __shared__ alignas(16) BF16 sK[2 * 8192];  // [buf][perm_key 128][d 64]
  __shared__ alignas(16) BF16 sV[2 * 8192];  // [buf][d 64][key 128]
  const int id = blockIdx.x;
  const int xcd = id & 7, local = id >> 3;      // blockIdx%8 round-robins XCDs
  const int bh = xcd * 4 + (local & 3);         // 4 (b,h) per XCD: 2MB K/V in L2
  const int s = 31 - (local >> 2);              // 64-row strip, long first
  const int b = bh >> 4, h = bh & 15;
  const int tid = threadIdx.x;
  const int wave = tid >> 6, lane = tid & 63;
  const int quad = lane >> 4, l16 = lane & 15;
  const size_t base = ((size_t)(b * Hh + h)) * Tt * Dd;
  const int qrow0 = s * 64 + wave * 16;
  const int sw = l16 & 7;

  // Q fragment (B-operand: lane n=l16 holds Q[qrow0+l16][k=quad*8+j])
  bf16x8 qf0, qf1;
  {
    const size_t off = base + (size_t)(qrow0 + l16) * Dd;
    qf0 = *(const bf16x8*)&qg[off + quad * 8];
    qf1 = *(const bf16x8*)&qg[off + 32 + quad * 8];
  }

  bf16x8 ones8;
#pragma unroll
  for (int j = 0; j < 8; ++j) ones8[j] = (__bf16)1.0f;

  f32x4 o[4], oL;
#pragma unroll
  for (int i = 0; i < 4; ++i) o[i] = f32x4{0.f, 0.f, 0.f, 0.f};
  oL = f32x4{0.f, 0.f, 0.f, 0.f};

  const f32x4 cbias = f32x4{-EXP2_BIAS, -EXP2_BIAS, -EXP2_BIAS, -EXP2_BIAS};

  // Staging (per thread, 4 K + 4 V gll16 per tile).
  const int t = tid;
  const int sgk = (t ^ (t >> 3)) & 7;
  const int sgv = (t ^ (t >> 4)) & 15;
  const BF16* pk[4];
  const BF16* pv[4];
#pragma unroll
  for (int i = 0; i < 4; ++i) {
    pk[i] = &kg[base + (size_t)kperm_inv7(i * 32 + (t >> 3)) * Dd + sgk * 8];
    pv[i] = &vtg[base + (size_t)(i * 16 + (t >> 4)) * Tt + sgv * 8];
  }

#define STAGE_K(buf, tt_)                                            \
  do {                                                               \
    const size_t ko_ = (size_t)(tt_) * 8192;                         \
    _Pragma("unroll") for (int i_ = 0; i_ < 4; ++i_)                 \
        gll16(pk[i_] + ko_, &sK[(buf) * 8192 + i_ * 2048 + t * 8]);  \
  } while (0)
#define STAGE_V(buf, tt_)                                            \
  do {                                                               \
    const int vo_ = (tt_) * 128;                                     \
    _Pragma("unroll") for (int i_ = 0; i_ < 4; ++i_)                 \
        gll16(pv[i_] + vo_, &sV[(buf) * 8192 + i_ * 2048 + t * 8]);  \
  } while (0)

#define QK_TILE(jt_)                                                        \
  do {                                                                      \
    const BF16* sKb_ = &sK[((jt_) & 1) * 8192];                             \
    __builtin_amdgcn_s_setprio(1);                                          \
    _Pragma("unroll") for (int tt = 0; tt < 8; ++tt) {                      \
      const bf16x8 kf0 =                                                    \
          *(const bf16x8*)&sKb_[(tt * 16 + l16) * 64 + ((quad ^ sw) << 3)]; \
      const bf16x8 kf1 = *(const bf16x8*)                                   \
          &sKb_[(tt * 16 + l16) * 64 + (((4 + quad) ^ sw) << 3)];           \
      sS[tt] = mfma16(kf0, qf0, cbias);                                     \
      sS[tt] = mfma16(kf1, qf1, sS[tt]);                                    \
    }                                                                       \
    __builtin_amdgcn_s_setprio(0);                                          \
  } while (0)

#define MASK_TILE(jt_)                                                  \
  do {                                                                  \
    const int kb_ = (jt_) * 128;                                        \
    const int q_ = qrow0 + l16;                                         \
    _Pragma("unroll") for (int tt = 0; tt < 8; ++tt) {                  \
      const int kc0 = kb_ + (tt >> 1) * 32 + quad * 8 + (tt & 1) * 4;   \
      _Pragma("unroll") for (int r = 0; r < 4; ++r)                     \
          if (kc0 + r > q_) sS[tt][r] = NEG_INF;                        \
    }                                                                   \
  } while (0)

#define EXP_P()                                                          \
  do {                                                                   \
    _Pragma("unroll") for (int cc = 0; cc < 4; ++cc)                     \
        _Pragma("unroll") for (int j = 0; j < 8; ++j)                    \
            pf[cc][j] = (__bf16)fast_exp2(sS[cc * 2 + (j >> 2)][j & 3]); \
  } while (0)

#define PV_TILE(jt_)                                                          \
  do {                                                                        \
    const BF16* sVb_ = &sV[((jt_) & 1) * 8192];                               \
    __builtin_amdgcn_s_setprio(1);                                            \
    _Pragma("unroll") for (int cc = 0; cc < 4; ++cc) {                        \
      _Pragma("unroll") for (int dt = 0; dt < 4; ++dt) {                      \
        const bf16x8 vb = *(const bf16x8*)                                    \
            &sVb_[(dt * 16 + l16) * 128 +                                     \
                  ((((cc * 4 + quad) ^ l16) & 15) << 3)];                     \
        o[dt] = mfma16(pf[cc], vb, o[dt]);                                    \
      }                                                                       \
      oL = mfma16(pf[cc], ones8, oL);                                         \
    }                                                                         \
    __builtin_amdgcn_s_setprio(0);                                            \
  } while (0)

  const int nt = (s + 2) >> 1;  // tiles of 128 keys
  f32x4 sS[8];
  bf16x8 pf[4];

  // prologue: K(0) in flight
  STAGE_K(0, 0);

  // iter 0: QK(0) only
  asm volatile("s_waitcnt vmcnt(0)" ::: "memory");
  __builtin_amdgcn_s_barrier();
  STAGE_V(0, 0);
  if (nt > 1) STAGE_K(1, 1);
  QK_TILE(0);
  if (nt == 1) MASK_TILE(0);

  // main iters 1..nt-1: exp/PV(jt-1) || QK(jt)
  for (int jt = 1; jt < nt; ++jt) {
    asm volatile("s_waitcnt vmcnt(0)" ::: "memory");
    __builtin_amdgcn_s_barrier();
    STAGE_V(jt & 1, jt);
    if (jt + 1 < nt) STAGE_K((jt + 1) & 1, jt + 1);
    EXP_P();       // VALU, reads sS of tile jt-1 (independent of QK below)
    QK_TILE(jt);   // MFMA, overlaps EXP_P in the same straight-line block
    if (jt == nt - 1) MASK_TILE(jt);
    PV_TILE(jt - 1);
  }

  // final iter nt: exp/PV of tile nt-1
  asm volatile("s_waitcnt vmcnt(0)" ::: "memory");
  __builtin_amdgcn_s_barrier();
  EXP_P();
  PV_TILE(nt - 1);

#undef STAGE_K
#undef STAGE_V
#undef QK_TILE
#undef MASK_TILE
#undef EXP_P
#undef PV_TILE

  // epilogue: C-layout row quad*4+r = q, col dt*16+l16 = d
#pragma unroll
  for (int r = 0; r < 4; ++r) {
    const float inv = 1.0f / oL[r];
    const int trow = qrow0 + quad * 4 + r;
#pragma unroll
    for (int dt = 0; dt < 4; ++dt)
      yb[((size_t)(b * Tt + trow)) * Cc + h * Dd + dt * 16 + l16] =
          __float2bfloat16(o[dt][r] * inv);
  }
}

extern "C" void kernel_launch(void* const* d_in, const int* in_sizes, int n_in,
                              void* d_out, int out_size, void* d_ws, size_t ws_size,
                              hipStream_t stream) {
  (void)in_sizes; (void)n_in; (void)out_size; (void)ws_size;
  const float* x      = (const float*)d_in[0];
  const float* W_attn = (const float*)d_in[1];
  const float* b_attn = (const float*)d_in[2];
  const float* W_proj = (const float*)d_in[3];
  const float* b_proj = (const float*)d_in[4];
  float* out = (float*)d_out;

  constexpr size_t SZ_WA = (size_t)3072 * 1024;
  constexpr size_t SZ_WP = (size_t)1024 * 1024;
  constexpr size_t SZ_X  = (size_t)4096 * 1024;
  constexpr size_t SZ_T  = (size_t)Bb * Hh * Tt * Dd;

  BF16* ws   = (BF16*)d_ws;
  BF16* wtAb = ws;
  BF16* wtPb = wtAb + SZ_WA;
  BF16* xb   = wtPb + SZ_WP;
  BF16* q    = xb + SZ_X;
  BF16* k    = q + SZ_T;
  BF16* vt   = k + SZ_T;
  BF16* yb   = vt + SZ_T;

  prep_kernel<<<dim3(6144), 256, 0, stream>>>(x, xb, W_attn, wtAb, W_proj, wtPb);
  gemm_qkv<<<dim3(1536), 256, 0, stream>>>(xb, wtAb, b_attn, q, k, vt);
  attn_kernel<<<dim3(1024), 256, 0, stream>>>(q, k, vt, yb);
  gemm_proj<<<dim3(16, 64), 256, 0, stream>>>(yb, wtPb, b_proj, out);
}